// Round 6
// baseline (309.914 us; speedup 1.0000x reference)
//
#include <hip/hip_runtime.h>

#define BN_EPS 1e-3f

typedef __attribute__((ext_vector_type(8))) short bf16x8;
typedef __attribute__((ext_vector_type(16))) float floatx16;
typedef unsigned short u16;

__device__ __forceinline__ u16 f2bf(float f) {
  unsigned u = __float_as_uint(f);
  u += 0x7fffu + ((u >> 16) & 1u);   // RNE
  return (u16)(u >> 16);
}
__device__ __forceinline__ float bf2f(u16 h) {
  return __uint_as_float(((unsigned)h) << 16);
}

static constexpr int NSHARD = 64;   // stats shards (128 floats each)

// ---------------------------------------------------------------------------
// conv1: x[be][28][28] * k1[b][9][64] -> y1 bf16 [be][196][64] + sharded
// per-channel sum/sumsq.  Padded 30x30 LDS input -> branch-free inner loop.
// ---------------------------------------------------------------------------
__global__ __launch_bounds__(256) void conv1_kernel(
    const float* __restrict__ x, const float* __restrict__ k1,
    u16* __restrict__ y1, float* __restrict__ statsSh)
{
  __shared__ float xp[900];   // 30x30, zero border
  __shared__ float w1[576];
  __shared__ float red[256];

  const int be = blockIdx.x, b = be >> 6, tid = threadIdx.x;

  for (int i = tid; i < 900; i += 256) xp[i] = 0.f;
  for (int i = tid; i < 576; i += 256) w1[i] = k1[(size_t)b * 576 + i];
  __syncthreads();
  for (int i = tid; i < 784; i += 256) {
    const int r = i / 28, cc = i - 28 * r;
    xp[(r + 1) * 30 + (cc + 1)] = x[(size_t)be * 784 + i];
  }
  __syncthreads();

  const int c = tid & 63;
  float wr[9];
#pragma unroll
  for (int t = 0; t < 9; ++t) wr[t] = w1[t * 64 + c];

  float sum = 0.f, ss = 0.f;
  for (int pix = tid >> 6; pix < 196; pix += 4) {
    const int oy = pix / 14, ox = pix - 14 * oy;
    const float* xb = &xp[(2 * oy) * 30 + 2 * ox];
    float acc = 0.f;
#pragma unroll
    for (int ky = 0; ky < 3; ++ky)
#pragma unroll
      for (int kx = 0; kx < 3; ++kx)
        acc = fmaf(xb[ky * 30 + kx], wr[ky * 3 + kx], acc);
    const float v = fmaxf(acc, 0.f);
    y1[((size_t)be * 196 + pix) * 64 + c] = f2bf(v);
    sum += v;
    ss = fmaf(v, v, ss);
  }

  red[tid] = sum;
  __syncthreads();
  if (tid < 64)
    atomicAdd(&statsSh[(blockIdx.x & (NSHARD - 1)) * 128 + tid],
              red[tid] + red[tid + 64] + red[tid + 128] + red[tid + 192]);
  __syncthreads();
  red[tid] = ss;
  __syncthreads();
  if (tid < 64)
    atomicAdd(&statsSh[(blockIdx.x & (NSHARD - 1)) * 128 + 64 + tid],
              red[tid] + red[tid + 64] + red[tid + 128] + red[tid + 192]);
}

// ---------------------------------------------------------------------------
// fold: block (task, slice-triple).  Reduce stats shards -> s,t; emit
// Wf bf16 [b][s][cout][cin] scaled by s_cin; atomically accumulate the
// 9-class boundary bias table bias[b][cls][cout] (zeroed by memset).
// ---------------------------------------------------------------------------
__global__ __launch_bounds__(256) void fold_kernel(
    const float* __restrict__ W, const float* __restrict__ statsSh, float invN,
    u16* __restrict__ Wf, float* __restrict__ biasCls)
{
  __shared__ float T[64 * 68];
  __shared__ float P[256];
  __shared__ float s1[64], t1[64];
  __shared__ float tbS[64];

  const int b = blockIdx.x / 3, sg = blockIdx.x % 3;
  const int tid = threadIdx.x;

  {  // reduce NSHARD shards x 128 stats
    const int g = tid >> 7, cidx = tid & 127;
    float acc = 0.f;
    for (int k = 0; k < NSHARD / 2; ++k)
      acc += statsSh[(g * (NSHARD / 2) + k) * 128 + cidx];
    P[tid] = acc;
  }
  __syncthreads();
  if (tid < 64) {
    const float m = (P[tid] + P[tid + 128]) * invN;
    const float var = fmaf(-m, m, (P[64 + tid] + P[192 + tid]) * invN);
    const float s = rsqrtf(var + BN_EPS);
    s1[tid] = s;
    t1[tid] = -m * s;
  }
  __syncthreads();

  const int cin = tid >> 2, q0 = (tid & 3) * 16;     // pass 1 mapping
  const int cout = tid >> 2, ci0 = (tid & 3) * 16;   // pass 2 mapping
  for (int s = sg * 3; s < sg * 3 + 3; ++s) {
    if (tid < 64) tbS[tid] = 0.f;
    const float* ss = W + ((size_t)b * 9 + s) * 4096;
#pragma unroll
    for (int q = 0; q < 16; q += 4) {
      const float4 v = *(const float4*)(ss + cin * 64 + q0 + q);
      T[(q0 + q + 0) * 68 + cin] = v.x;
      T[(q0 + q + 1) * 68 + cin] = v.y;
      T[(q0 + q + 2) * 68 + cin] = v.z;
      T[(q0 + q + 3) * 68 + cin] = v.w;
    }
    __syncthreads();
    alignas(16) u16 tmp[16];
    float tb = 0.f;
#pragma unroll
    for (int j = 0; j < 16; ++j) {
      const float wv = T[cout * 68 + ci0 + j];
      tmp[j] = f2bf(wv * s1[ci0 + j]);
      tb = fmaf(t1[ci0 + j], wv, tb);
    }
    u16* dst = Wf + ((size_t)b * 9 + s) * 4096 + cout * 64 + ci0;
    *(uint4*)dst       = *(uint4*)&tmp[0];
    *(uint4*)(dst + 8) = *(uint4*)&tmp[8];
    atomicAdd(&tbS[cout], tb);
    __syncthreads();
    if (tid < 64) {
      const int ky = s / 3, kx = s % 3;
      const float tv = tbS[tid];
#pragma unroll
      for (int cls = 0; cls < 9; ++cls) {
        const int ry = cls / 3, rx = cls % 3;
        const bool valid = !((ry == 1 && ky == 0) || (ry == 2 && ky == 2) ||
                             (rx == 1 && kx == 0) || (rx == 2 && kx == 2));
        if (valid) atomicAdd(&biasCls[(size_t)b * 576 + cls * 64 + tid], tv);
      }
    }
    __syncthreads();
  }
}

// ---------------------------------------------------------------------------
// conv_gemm: layers 2..4.  M=128 rows (G images x Hout^2, zero-padded), N=64
// couts, K = 9 slices x 64 cin.  4 waves, each: 1 m-tile x 2 n-tiles of
// 32x32x16 bf16 MFMA.  Global->reg prefetch of slice s+1 overlaps compute.
// BN folded into Wf + boundary-class bias; ReLU; bf16 out; sharded stats.
// ---------------------------------------------------------------------------
template <int Hin, int Hout, int G>
__global__ __launch_bounds__(256) void conv_gemm_kernel(
    const u16* __restrict__ yin, const u16* __restrict__ Wf,
    const float* __restrict__ biasCls, u16* __restrict__ yout,
    float* __restrict__ statsSh)
{
  constexpr int PPI  = Hout * Hout;
  constexpr int ROWS = G * PPI;          // <= 128
  constexpr int BPT  = 64 / G;
  constexpr int LDA  = 68;               // u16 stride: 2-way banking (free)

  __shared__ __align__(16) u16 AS[128 * LDA];   // 17 KB
  __shared__ __align__(16) u16 BtS[64 * LDA];   // 8.5 KB
  __shared__ float biasS[576];
  __shared__ float redsum[64], redss[64];

  const int b = blockIdx.x / BPT;
  const int e0 = (blockIdx.x % BPT) * G;
  const int tid = threadIdx.x, lane = tid & 63, wave = tid >> 6;

  for (int i = tid; i < 576; i += 256) biasS[i] = biasCls[(size_t)b * 576 + i];
  if (tid < 64) { redsum[tid] = 0.f; redss[tid] = 0.f; }

  // A staging: row = tid>>1 (0..127), 32 channels at ci0
  const int arow = tid >> 1, ci0 = (tid & 1) * 32;
  const bool rowOk = arow < ROWS;
  const int g = rowOk ? arow / PPI : 0;
  const int pp = rowOk ? arow % PPI : 0;
  const int oy = pp / Hout, ox = pp % Hout;
  const size_t inBase = ((size_t)(b * 64 + e0 + g)) * (Hin * Hin) * 64;

  // B staging: bco = tid>>2, 16 channels at bci
  const int bco = tid >> 2, bci = (tid & 3) * 16;
  const u16* wbase = Wf + (size_t)b * 9 * 4096 + bco * 64 + bci;

  uint4 pa0, pa1, pa2, pa3, pb0, pb1;
  auto loadSlice = [&](int s) {
    const int ky = s / 3, kx = s % 3;
    const int iy = 2 * oy - 1 + ky, ix = 2 * ox - 1 + kx;
    if (rowOk && (unsigned)iy < (unsigned)Hin && (unsigned)ix < (unsigned)Hin) {
      const u16* src = yin + inBase + (size_t)(iy * Hin + ix) * 64 + ci0;
      pa0 = *(const uint4*)(src);
      pa1 = *(const uint4*)(src + 8);
      pa2 = *(const uint4*)(src + 16);
      pa3 = *(const uint4*)(src + 24);
    } else {
      pa0 = pa1 = pa2 = pa3 = uint4{0, 0, 0, 0};
    }
    const u16* wsl = wbase + s * 4096;
    pb0 = *(const uint4*)wsl;
    pb1 = *(const uint4*)(wsl + 8);
  };

  // compute mapping: wave owns m-tile [wave*32, wave*32+32) x both n-tiles
  const int m0 = wave * 32;
  const int l31 = lane & 31;
  const int kq = (lane >> 5) * 8;

  floatx16 acc0, acc1;
#pragma unroll
  for (int r = 0; r < 16; ++r) { acc0[r] = 0.f; acc1[r] = 0.f; }

  loadSlice(0);
#pragma unroll
  for (int s = 0; s < 9; ++s) {
    *(uint4*)&AS[arow * LDA + ci0]      = pa0;
    *(uint4*)&AS[arow * LDA + ci0 + 8]  = pa1;
    *(uint4*)&AS[arow * LDA + ci0 + 16] = pa2;
    *(uint4*)&AS[arow * LDA + ci0 + 24] = pa3;
    *(uint4*)&BtS[bco * LDA + bci]     = pb0;
    *(uint4*)&BtS[bco * LDA + bci + 8] = pb1;
    __syncthreads();
    if (s < 8) loadSlice(s + 1);   // prefetch overlaps the MFMA phase
#pragma unroll
    for (int kk = 0; kk < 4; ++kk) {
      const int ko = kk * 16 + kq;
      bf16x8 a  = *(const bf16x8*)&AS[(m0 + l31) * LDA + ko];
      bf16x8 b0 = *(const bf16x8*)&BtS[l31 * LDA + ko];
      bf16x8 b1 = *(const bf16x8*)&BtS[(32 + l31) * LDA + ko];
      acc0 = __builtin_amdgcn_mfma_f32_32x32x16_bf16(a, b0, acc0, 0, 0, 0);
      acc1 = __builtin_amdgcn_mfma_f32_32x32x16_bf16(a, b1, acc1, 0, 0, 0);
    }
    __syncthreads();
  }

  // epilogue: bias by boundary class, ReLU, bf16 store, stats
  float ls0 = 0.f, lss0 = 0.f, ls1 = 0.f, lss1 = 0.f;
  const int col0 = l31, col1 = 32 + l31;
  const int rb = m0 + 4 * (lane >> 5);
#pragma unroll
  for (int r = 0; r < 16; ++r) {
    const int rw = rb + (r & 3) + 8 * (r >> 2);
    if (rw < ROWS) {
      const int re = rw / PPI, pr = rw % PPI;
      const int ooy = pr / Hout, oox = pr % Hout;
      const int ry = (ooy == 0) ? 1 : ((2 * ooy + 1 >= Hin) ? 2 : 0);
      const int rx = (oox == 0) ? 1 : ((2 * oox + 1 >= Hin) ? 2 : 0);
      const int cls = ry * 3 + rx;
      const size_t ob = ((size_t)(b * 64 + e0 + re) * PPI + pr) * 64;
      const float v0 = fmaxf(acc0[r] + biasS[cls * 64 + col0], 0.f);
      const float v1 = fmaxf(acc1[r] + biasS[cls * 64 + col1], 0.f);
      yout[ob + col0] = f2bf(v0);
      yout[ob + col1] = f2bf(v1);
      ls0 += v0; lss0 = fmaf(v0, v0, lss0);
      ls1 += v1; lss1 = fmaf(v1, v1, lss1);
    }
  }
  atomicAdd(&redsum[col0], ls0);
  atomicAdd(&redss[col0], lss0);
  atomicAdd(&redsum[col1], ls1);
  atomicAdd(&redss[col1], lss1);
  __syncthreads();
  if (tid < 64) {
    const int sh = blockIdx.x & (NSHARD - 1);
    atomicAdd(&statsSh[sh * 128 + tid], redsum[tid]);
    atomicAdd(&statsSh[sh * 128 + 64 + tid], redss[tid]);
  }
}

// ---------------------------------------------------------------------------
// readout: reduce stats4 shards, feat = BN(maxpool(y4)), out = feat @ w_ro[b].
// ---------------------------------------------------------------------------
__global__ __launch_bounds__(256) void readout_kernel(
    const u16* __restrict__ y4, const float* __restrict__ w_ro,
    const float* __restrict__ statsSh, float invN, float* __restrict__ outp)
{
  __shared__ float wl[64 * 20];
  __shared__ float feat[64 * 64];
  __shared__ float P[256];
  __shared__ float sArr[64], tArr[64];

  const int b = blockIdx.x, tid = threadIdx.x;

  {
    const int g = tid >> 7, cidx = tid & 127;
    float acc = 0.f;
    for (int k = 0; k < NSHARD / 2; ++k)
      acc += statsSh[(g * (NSHARD / 2) + k) * 128 + cidx];
    P[tid] = acc;
  }
  for (int i = tid; i < 1280; i += 256) wl[i] = w_ro[(size_t)b * 1280 + i];
  __syncthreads();
  if (tid < 64) {
    const float m = (P[tid] + P[tid + 128]) * invN;
    const float var = fmaf(-m, m, (P[64 + tid] + P[192 + tid]) * invN);
    const float s = rsqrtf(var + BN_EPS);
    sArr[tid] = s;
    tArr[tid] = -m * s;
  }
  __syncthreads();

  {
    const int e = tid & 63;
    for (int c = tid >> 6; c < 64; c += 4) {
      const u16* p4 = y4 + ((size_t)(b * 64 + e) * 4) * 64 + c;
      const float v = fmaxf(fmaxf(bf2f(p4[0]), bf2f(p4[64])),
                            fmaxf(bf2f(p4[128]), bf2f(p4[192])));
      feat[c * 64 + e] = fmaf(v, sArr[c], tArr[c]);
    }
  }
  __syncthreads();

  const int e = tid >> 2, og = (tid & 3) * 5;
  float acc[5] = {0.f, 0.f, 0.f, 0.f, 0.f};
  for (int c = 0; c < 64; ++c) {
    const float f = feat[c * 64 + e];
#pragma unroll
    for (int j = 0; j < 5; ++j) acc[j] = fmaf(f, wl[c * 20 + og + j], acc[j]);
  }
#pragma unroll
  for (int j = 0; j < 5; ++j)
    outp[((size_t)b * 64 + e) * 20 + og + j] = acc[j];
}

// ---------------------------------------------------------------------------
extern "C" void kernel_launch(void* const* d_in, const int* in_sizes, int n_in,
                              void* d_out, int out_size, void* d_ws, size_t ws_size,
                              hipStream_t stream) {
  (void)in_sizes; (void)n_in; (void)out_size; (void)ws_size;
  const float* x   = (const float*)d_in[0];
  const float* k1  = (const float*)d_in[1];
  const float* k2  = (const float*)d_in[2];
  const float* k3  = (const float*)d_in[3];
  const float* k4  = (const float*)d_in[4];
  const float* wro = (const float*)d_in[5];
  float* out = (float*)d_out;
  char* ws = (char*)d_ws;

  // ws layout (bytes), total ~143 MB:
  //  stats: 4 layers x 64 shards x 128 f32         = 131072
  //  bias2/3/4: 64 x 576 f32                       = 3 x 147456  (memset w/ stats)
  //  k2f/k3f/k4f bf16                              = 3 x 4718592
  //  y2 bf16 [4096][49][64]                        = 25690112
  //  y1 bf16 [4096][196][64]                       = 102760448 (y3/y4 alias in)
  float* stats = (float*)ws;
  float* bias2 = (float*)(ws + 131072);
  float* bias3 = bias2 + 36864;
  float* bias4 = bias3 + 36864;
  u16* k2f = (u16*)(ws + 131072 + 442368);
  u16* k3f = k2f + (size_t)2359296;
  u16* k4f = k3f + (size_t)2359296;
  u16* y2 = k4f + (size_t)2359296;
  u16* y1 = y2 + (size_t)12845056;
  u16* y3 = y1;                      // alias: y1 dead after conv2
  u16* y4 = y3 + (size_t)4194304;

  float* st1 = stats;
  float* st2 = stats + 8192;
  float* st3 = stats + 16384;
  float* st4 = stats + 24576;

  hipMemsetAsync(stats, 0, 131072 + 442368, stream);

  conv1_kernel<<<4096, 256, 0, stream>>>(x, k1, y1, st1);
  fold_kernel<<<192, 256, 0, stream>>>(k2, st1, 1.f / 802816.f, k2f, bias2);
  conv_gemm_kernel<14, 7, 2><<<2048, 256, 0, stream>>>(y1, k2f, bias2, y2, st2);
  fold_kernel<<<192, 256, 0, stream>>>(k3, st2, 1.f / 200704.f, k3f, bias3);
  conv_gemm_kernel<7, 4, 8><<<512, 256, 0, stream>>>(y2, k3f, bias3, y3, st3);
  fold_kernel<<<192, 256, 0, stream>>>(k4, st3, 1.f / 65536.f, k4f, bias4);
  conv_gemm_kernel<4, 2, 32><<<128, 256, 0, stream>>>(y3, k4f, bias4, y4, st4);
  readout_kernel<<<64, 256, 0, stream>>>(y4, wro, st4, 1.f / 16384.f, out);
}

// Round 7
// 265.265 us; speedup vs baseline: 1.1683x; 1.1683x over previous
//
#include <hip/hip_runtime.h>

#define BN_EPS 1e-3f

typedef __attribute__((ext_vector_type(8))) short bf16x8;
typedef __attribute__((ext_vector_type(16))) float floatx16;
typedef unsigned short u16;

__device__ __forceinline__ u16 f2bf(float f) {
  unsigned u = __float_as_uint(f);
  u += 0x7fffu + ((u >> 16) & 1u);   // RNE
  return (u16)(u >> 16);
}
__device__ __forceinline__ float bf2f(u16 h) {
  return __uint_as_float(((unsigned)h) << 16);
}

static constexpr int NSHARD = 64;   // stats shards (128 floats each)

// ---------------------------------------------------------------------------
// conv1: x[be][28][28] * k1[b][9][64] -> y1 bf16 [be][196][64] + sharded
// stats.  Thread = (output row oy, 4-channel group): 3 input rows (87 f32)
// and 36 weights in REGISTERS -> 504 FMA with ~123 LDS reads (was 441).
// ---------------------------------------------------------------------------
__global__ __launch_bounds__(256) void conv1_k(
    const float* __restrict__ x, const float* __restrict__ k1,
    u16* __restrict__ y1, float* __restrict__ statsSh)
{
  __shared__ float xp[30 * 32];   // rows stride 32, zero border
  __shared__ float w1s[576];
  __shared__ float redsum[64], redss[64];

  const int be = blockIdx.x, b = be >> 6, tid = threadIdx.x;

  for (int i = tid; i < 960; i += 256) xp[i] = 0.f;
  for (int i = tid; i < 576; i += 256) w1s[i] = k1[(size_t)b * 576 + i];
  if (tid < 64) { redsum[tid] = 0.f; redss[tid] = 0.f; }
  __syncthreads();
  for (int i = tid; i < 784; i += 256) {
    const int r = i / 28, c = i - 28 * r;
    xp[(r + 1) * 32 + (c + 1)] = x[(size_t)be * 784 + i];
  }
  __syncthreads();

  if (tid < 224) {
    const int oy = tid >> 4, cg = (tid & 15) * 4;
    float w[4][9];
#pragma unroll
    for (int cc = 0; cc < 4; ++cc)
#pragma unroll
      for (int t = 0; t < 9; ++t) w[cc][t] = w1s[t * 64 + cg + cc];

    float xr[3][29];
#pragma unroll
    for (int ky = 0; ky < 3; ++ky)
#pragma unroll
      for (int j = 0; j < 29; ++j) xr[ky][j] = xp[(2 * oy + ky) * 32 + j];

    float sum[4] = {0.f, 0.f, 0.f, 0.f}, ss[4] = {0.f, 0.f, 0.f, 0.f};
#pragma unroll
    for (int ox = 0; ox < 14; ++ox) {
      alignas(8) u16 o[4];
#pragma unroll
      for (int cc = 0; cc < 4; ++cc) {
        float a = 0.f;
#pragma unroll
        for (int ky = 0; ky < 3; ++ky)
#pragma unroll
          for (int kx = 0; kx < 3; ++kx)
            a = fmaf(xr[ky][2 * ox + kx], w[cc][ky * 3 + kx], a);
        const float v = fmaxf(a, 0.f);
        o[cc] = f2bf(v);
        sum[cc] += v;
        ss[cc] = fmaf(v, v, ss[cc]);
      }
      *(uint2*)&y1[((size_t)be * 196 + oy * 14 + ox) * 64 + cg] = *(uint2*)o;
    }
#pragma unroll
    for (int cc = 0; cc < 4; ++cc) {
      atomicAdd(&redsum[cg + cc], sum[cc]);
      atomicAdd(&redss[cg + cc], ss[cc]);
    }
  }
  __syncthreads();
  if (tid < 64) {
    const int sh = be & (NSHARD - 1);
    atomicAdd(&statsSh[sh * 128 + tid], redsum[tid]);
    atomicAdd(&statsSh[sh * 128 + 64 + tid], redss[tid]);
  }
}

// ---------------------------------------------------------------------------
// fold: block (task, slice-triple).  Reduce stats shards -> s,t; emit
// Wf bf16 [b][s][cout][cin] scaled by s_cin; accumulate 9-class boundary
// bias table bias[b][cls][cout] (zeroed by memset).
// ---------------------------------------------------------------------------
__global__ __launch_bounds__(256) void foldw_k(
    const float* __restrict__ W, const float* __restrict__ statsSh, float invN,
    u16* __restrict__ Wf, float* __restrict__ biasCls)
{
  __shared__ float T[64 * 68];
  __shared__ float P[256];
  __shared__ float s1[64], t1[64];
  __shared__ float tbS[64];

  const int b = blockIdx.x / 3, sg = blockIdx.x % 3;
  const int tid = threadIdx.x;

  {
    const int g = tid >> 7, cidx = tid & 127;
    float acc = 0.f;
    for (int k = 0; k < NSHARD / 2; ++k)
      acc += statsSh[(g * (NSHARD / 2) + k) * 128 + cidx];
    P[tid] = acc;
  }
  __syncthreads();
  if (tid < 64) {
    const float m = (P[tid] + P[tid + 128]) * invN;
    const float var = fmaf(-m, m, (P[64 + tid] + P[192 + tid]) * invN);
    const float s = rsqrtf(var + BN_EPS);
    s1[tid] = s;
    t1[tid] = -m * s;
  }
  __syncthreads();

  const int cin = tid >> 2, q0 = (tid & 3) * 16;
  const int cout = tid >> 2, ci0 = (tid & 3) * 16;
  for (int s = sg * 3; s < sg * 3 + 3; ++s) {
    if (tid < 64) tbS[tid] = 0.f;
    const float* ss = W + ((size_t)b * 9 + s) * 4096;
#pragma unroll
    for (int q = 0; q < 16; q += 4) {
      const float4 v = *(const float4*)(ss + cin * 64 + q0 + q);
      T[(q0 + q + 0) * 68 + cin] = v.x;
      T[(q0 + q + 1) * 68 + cin] = v.y;
      T[(q0 + q + 2) * 68 + cin] = v.z;
      T[(q0 + q + 3) * 68 + cin] = v.w;
    }
    __syncthreads();
    alignas(16) u16 tmp[16];
    float tb = 0.f;
#pragma unroll
    for (int j = 0; j < 16; ++j) {
      const float wv = T[cout * 68 + ci0 + j];
      tmp[j] = f2bf(wv * s1[ci0 + j]);
      tb = fmaf(t1[ci0 + j], wv, tb);
    }
    u16* dst = Wf + ((size_t)b * 9 + s) * 4096 + cout * 64 + ci0;
    *(uint4*)dst       = *(uint4*)&tmp[0];
    *(uint4*)(dst + 8) = *(uint4*)&tmp[8];
    atomicAdd(&tbS[cout], tb);
    __syncthreads();
    if (tid < 64) {
      const int ky = s / 3, kx = s % 3;
      const float tv = tbS[tid];
#pragma unroll
      for (int cls = 0; cls < 9; ++cls) {
        const int ry = cls / 3, rx = cls % 3;
        const bool valid = !((ry == 1 && ky == 0) || (ry == 2 && ky == 2) ||
                             (rx == 1 && kx == 0) || (rx == 2 && kx == 2));
        if (valid) atomicAdd(&biasCls[(size_t)b * 576 + cls * 64 + tid], tv);
      }
    }
    __syncthreads();
  }
}

// ---------------------------------------------------------------------------
// conv_core: G input images staged ONCE in LDS (zero-row for borders,
// stride 72 -> conflict-free).  K-loop: only B (8 KB/slice) moves, LDS
// double-buffered via plain register staging.  M=64 x N=64, 4 waves,
// 1 acc/wave of 32x32x16 bf16 MFMA.  One barrier per slice.
// ---------------------------------------------------------------------------
template <int Hin, int Hout, int G>
__device__ __forceinline__ void conv_core(
    const u16* __restrict__ yin, const u16* __restrict__ Wf,
    const float* __restrict__ biasCls, u16* __restrict__ yout,
    float* __restrict__ statsSh, int blk)
{
  constexpr int PPI  = Hout * Hout;
  constexpr int ROWS = G * PPI;          // <= 64
  constexpr int BPT  = 64 / G;
  constexpr int MR   = G * Hin * Hin;    // map rows
  constexpr int ZR   = MR;               // zero row index

  __shared__ __align__(16) u16 mapS[(MR + 1) * 72];
  __shared__ __align__(16) u16 Bb[2][64 * 72];
  __shared__ float biasS[576];
  __shared__ float redsum[64], redss[64];

  const int b = blk / BPT, e0 = (blk % BPT) * G;
  const int tid = threadIdx.x, lane = tid & 63, wave = tid >> 6;

  for (int i = tid; i < 576; i += 256) biasS[i] = biasCls[(size_t)b * 576 + i];
  if (tid < 64) { redsum[tid] = 0.f; redss[tid] = 0.f; }
  if (tid < 8) *(uint4*)&mapS[ZR * 72 + tid * 8] = uint4{0, 0, 0, 0};

  // stage the G-image group (contiguous in yin) into the map
  {
    const u16* src = yin + (size_t)(b * 64 + e0) * (Hin * Hin) * 64;
    for (int ch = tid; ch < MR * 8; ch += 256) {
      const int r = ch >> 3, c8 = ch & 7;
      *(uint4*)&mapS[r * 72 + c8 * 8] = *(const uint4*)(src + ch * 8);
    }
  }

  // B slice 0
  const int bco = tid >> 2, bci = (tid & 3) * 16;
  const u16* wb = Wf + (size_t)b * 9 * 4096 + bco * 64 + bci;
  {
    uint4 b0 = *(const uint4*)wb;
    uint4 b1 = *(const uint4*)(wb + 8);
    *(uint4*)&Bb[0][bco * 72 + bci]     = b0;
    *(uint4*)&Bb[0][bco * 72 + bci + 8] = b1;
  }

  const int m0 = (wave & 1) * 32, n0 = (wave >> 1) * 32;
  const int l31 = lane & 31, kq = (lane >> 5) * 8;
  const int lrow = m0 + l31;
  const bool rv = lrow < ROWS;
  const int img = rv ? lrow / PPI : 0;
  const int pp  = rv ? lrow % PPI : 0;
  const int oy = pp / Hout, ox = pp % Hout;

  floatx16 acc;
#pragma unroll
  for (int r = 0; r < 16; ++r) acc[r] = 0.f;

  __syncthreads();

#pragma unroll
  for (int s = 0; s < 9; ++s) {
    uint4 nb0, nb1;
    if (s < 8) {
      const u16* wsl = wb + (s + 1) * 4096;
      nb0 = *(const uint4*)wsl;
      nb1 = *(const uint4*)(wsl + 8);
    }
    const int ky = s / 3, kx = s % 3;
    int pix = ZR;
    if (rv) {
      const int iy = 2 * oy - 1 + ky, ix = 2 * ox - 1 + kx;
      if ((unsigned)iy < (unsigned)Hin && (unsigned)ix < (unsigned)Hin)
        pix = img * (Hin * Hin) + iy * Hin + ix;
    }
    const u16* ap = &mapS[pix * 72 + kq];
    const u16* bp = &Bb[s & 1][(n0 + l31) * 72 + kq];
#pragma unroll
    for (int kk = 0; kk < 4; ++kk) {
      bf16x8 a  = *(const bf16x8*)(ap + kk * 16);
      bf16x8 bv = *(const bf16x8*)(bp + kk * 16);
      acc = __builtin_amdgcn_mfma_f32_32x32x16_bf16(a, bv, acc, 0, 0, 0);
    }
    if (s < 8) {
      u16* d = &Bb[(s + 1) & 1][bco * 72 + bci];
      *(uint4*)d       = nb0;
      *(uint4*)(d + 8) = nb1;
    }
    __syncthreads();
  }

  // epilogue: boundary-class bias, ReLU, bf16 store, stats
  const int col = n0 + l31;
  const int rb = m0 + 4 * (lane >> 5);
  float ls = 0.f, lss = 0.f;
#pragma unroll
  for (int r = 0; r < 16; ++r) {
    const int rw = rb + (r & 3) + 8 * (r >> 2);
    if (rw < ROWS) {
      const int re = rw / PPI, pr = rw % PPI;
      const int ooy = pr / Hout, oox = pr % Hout;
      const int ry = (ooy == 0) ? 1 : ((2 * ooy + 1 >= Hin) ? 2 : 0);
      const int rx = (oox == 0) ? 1 : ((2 * oox + 1 >= Hin) ? 2 : 0);
      const float v = fmaxf(acc[r] + biasS[(ry * 3 + rx) * 64 + col], 0.f);
      yout[((size_t)(b * 64 + e0 + re) * PPI + pr) * 64 + col] = f2bf(v);
      ls += v;
      lss = fmaf(v, v, lss);
    }
  }
  atomicAdd(&redsum[col], ls);
  atomicAdd(&redss[col], lss);
  __syncthreads();
  if (tid < 64) {
    const int sh = blk & (NSHARD - 1);
    atomicAdd(&statsSh[sh * 128 + tid], redsum[tid]);
    atomicAdd(&statsSh[sh * 128 + 64 + tid], redss[tid]);
  }
}

__global__ __launch_bounds__(256) void cg2_k(
    const u16* __restrict__ yin, const u16* __restrict__ Wf,
    const float* __restrict__ biasCls, u16* __restrict__ yout,
    float* __restrict__ statsSh) {
  conv_core<14, 7, 1>(yin, Wf, biasCls, yout, statsSh, blockIdx.x);
}
__global__ __launch_bounds__(256) void cg3_k(
    const u16* __restrict__ yin, const u16* __restrict__ Wf,
    const float* __restrict__ biasCls, u16* __restrict__ yout,
    float* __restrict__ statsSh) {
  conv_core<7, 4, 4>(yin, Wf, biasCls, yout, statsSh, blockIdx.x);
}
__global__ __launch_bounds__(256) void cg4_k(
    const u16* __restrict__ yin, const u16* __restrict__ Wf,
    const float* __restrict__ biasCls, u16* __restrict__ yout,
    float* __restrict__ statsSh) {
  conv_core<4, 2, 16>(yin, Wf, biasCls, yout, statsSh, blockIdx.x);
}

// ---------------------------------------------------------------------------
// readout: reduce stats4 shards, feat = BN(maxpool(y4)), out = feat @ w_ro[b].
// ---------------------------------------------------------------------------
__global__ __launch_bounds__(256) void readout_k(
    const u16* __restrict__ y4, const float* __restrict__ w_ro,
    const float* __restrict__ statsSh, float invN, float* __restrict__ outp)
{
  __shared__ float wl[64 * 20];
  __shared__ float feat[64 * 64];
  __shared__ float P[256];
  __shared__ float sArr[64], tArr[64];

  const int b = blockIdx.x, tid = threadIdx.x;

  {
    const int g = tid >> 7, cidx = tid & 127;
    float acc = 0.f;
    for (int k = 0; k < NSHARD / 2; ++k)
      acc += statsSh[(g * (NSHARD / 2) + k) * 128 + cidx];
    P[tid] = acc;
  }
  for (int i = tid; i < 1280; i += 256) wl[i] = w_ro[(size_t)b * 1280 + i];
  __syncthreads();
  if (tid < 64) {
    const float m = (P[tid] + P[tid + 128]) * invN;
    const float var = fmaf(-m, m, (P[64 + tid] + P[192 + tid]) * invN);
    const float s = rsqrtf(var + BN_EPS);
    sArr[tid] = s;
    tArr[tid] = -m * s;
  }
  __syncthreads();

  {
    const int e = tid & 63;
    for (int c = tid >> 6; c < 64; c += 4) {
      const u16* p4 = y4 + ((size_t)(b * 64 + e) * 4) * 64 + c;
      const float v = fmaxf(fmaxf(bf2f(p4[0]), bf2f(p4[64])),
                            fmaxf(bf2f(p4[128]), bf2f(p4[192])));
      feat[c * 64 + e] = fmaf(v, sArr[c], tArr[c]);
    }
  }
  __syncthreads();

  const int e = tid >> 2, og = (tid & 3) * 5;
  float acc[5] = {0.f, 0.f, 0.f, 0.f, 0.f};
  for (int c = 0; c < 64; ++c) {
    const float f = feat[c * 64 + e];
#pragma unroll
    for (int j = 0; j < 5; ++j) acc[j] = fmaf(f, wl[c * 20 + og + j], acc[j]);
  }
#pragma unroll
  for (int j = 0; j < 5; ++j)
    outp[((size_t)b * 64 + e) * 20 + og + j] = acc[j];
}

// ---------------------------------------------------------------------------
extern "C" void kernel_launch(void* const* d_in, const int* in_sizes, int n_in,
                              void* d_out, int out_size, void* d_ws, size_t ws_size,
                              hipStream_t stream) {
  (void)in_sizes; (void)n_in; (void)out_size; (void)ws_size;
  const float* x   = (const float*)d_in[0];
  const float* k1  = (const float*)d_in[1];
  const float* k2  = (const float*)d_in[2];
  const float* k3  = (const float*)d_in[3];
  const float* k4  = (const float*)d_in[4];
  const float* wro = (const float*)d_in[5];
  float* out = (float*)d_out;
  char* ws = (char*)d_ws;

  // ws layout (bytes), total ~143 MB:
  //  stats: 4 layers x 64 shards x 128 f32         = 131072
  //  bias2/3/4: 64 x 576 f32                       = 3 x 147456  (memset w/ stats)
  //  k2f/k3f/k4f bf16                              = 3 x 4718592
  //  y2 bf16 [4096][49][64]                        = 25690112
  //  y1 bf16 [4096][196][64]                       = 102760448 (y3/y4 alias in)
  float* stats = (float*)ws;
  float* bias2 = (float*)(ws + 131072);
  float* bias3 = bias2 + 36864;
  float* bias4 = bias3 + 36864;
  u16* k2f = (u16*)(ws + 131072 + 442368);
  u16* k3f = k2f + (size_t)2359296;
  u16* k4f = k3f + (size_t)2359296;
  u16* y2 = k4f + (size_t)2359296;
  u16* y1 = y2 + (size_t)12845056;
  u16* y3 = y1;                      // alias: y1 dead after conv2
  u16* y4 = y3 + (size_t)4194304;

  float* st1 = stats;
  float* st2 = stats + 8192;
  float* st3 = stats + 16384;
  float* st4 = stats + 24576;

  hipMemsetAsync(stats, 0, 131072 + 442368, stream);

  conv1_k<<<4096, 256, 0, stream>>>(x, k1, y1, st1);
  foldw_k<<<192, 256, 0, stream>>>(k2, st1, 1.f / 802816.f, k2f, bias2);
  cg2_k<<<4096, 256, 0, stream>>>(y1, k2f, bias2, y2, st2);
  foldw_k<<<192, 256, 0, stream>>>(k3, st2, 1.f / 200704.f, k3f, bias3);
  cg3_k<<<1024, 256, 0, stream>>>(y2, k3f, bias3, y3, st3);
  foldw_k<<<192, 256, 0, stream>>>(k4, st3, 1.f / 65536.f, k4f, bias4);
  cg4_k<<<256, 256, 0, stream>>>(y3, k4f, bias4, y4, st4);
  readout_k<<<64, 256, 0, stream>>>(y4, wro, st4, 1.f / 16384.f, out);
}